// Round 10
// baseline (118.582 us; speedup 1.0000x reference)
//
#include <hip/hip_runtime.h>
#include <hip/hip_bf16.h>
#include <stdint.h>

typedef __attribute__((ext_vector_type(8))) short bf8;
typedef __attribute__((ext_vector_type(4))) float f4;
typedef __attribute__((ext_vector_type(16))) float f16f;
typedef __attribute__((ext_vector_type(4))) unsigned int u32x4;

#define MFMA16(a, b, c) __builtin_amdgcn_mfma_f32_16x16x32_bf16((a), (b), (c), 0, 0, 0)
#define MFMA32(a, b, c) __builtin_amdgcn_mfma_f32_32x32x16_bf16((a), (b), (c), 0, 0, 0)

static __device__ __forceinline__ short f2b(float f) {
  uint32_t x = __float_as_uint(f);
  x += 0x7fffu + ((x >> 16) & 1u);
  return (short)(x >> 16);
}

// pack two nonnegative f32 into 2x bf16 (round-half-up, <0.5 ulp bias)
static __device__ __forceinline__ uint32_t pk2(float a, float b) {
  return ((__float_as_uint(a) + 0x8000u) >> 16) |
         ((__float_as_uint(b) + 0x8000u) & 0xffff0000u);
}

static __device__ __forceinline__ bf8 mk_bf8(uint32_t w0, uint32_t w1,
                                             uint32_t w2, uint32_t w3) {
  union { u32x4 u; bf8 b; } t;
  t.u = (u32x4){w0, w1, w2, w3};
  return t.b;
}

// async global->LDS, 16B per lane; LDS dest = wave-uniform base + lane*16
static __device__ __forceinline__ void gload16(const short* g, void* l) {
  __builtin_amdgcn_global_load_lds(
      (const __attribute__((address_space(1))) void*)g,
      (__attribute__((address_space(3))) void*)l, 16, 0, 0);
}

// fused: f32->bf16 convert (x -> xb, 4 weights -> Wb) + rope table build.
__global__ void convert_kernel(const float* __restrict__ x,
                               const float* __restrict__ wq, const float* __restrict__ wk,
                               const float* __restrict__ wv, const float* __restrict__ wo,
                               short* __restrict__ xb, short* __restrict__ Wb,
                               float2* __restrict__ tab) {
  const int bid = blockIdx.x;
  if (bid >= 4096) {
    const int t = (bid - 4096) * 256 + threadIdx.x;
    const int s = t >> 5, i = t & 31;
    const float inv = powf(10000.0f, -(float)i * (1.0f / 32.0f));
    const float ang = (float)s * inv;
    float sv, cv;
    sincosf(ang, &sv, &cv);
    tab[t] = make_float2(cv, sv);
    return;
  }
  const size_t i = ((size_t)bid * 256 + threadIdx.x) * 8;
  const float* __restrict__ src;
  short* __restrict__ dst;
  if (i < 4194304u) {
    src = x + i;
    dst = xb + i;
  } else {
    const size_t j = i - 4194304u;
    const int z = (int)(j >> 20);
    const size_t o = j & 1048575u;
    src = (z == 0 ? wq : z == 1 ? wk : z == 2 ? wv : wo) + o;
    dst = Wb + j;
  }
  const float4 a = *(const float4*)src;
  const float4 b = *(const float4*)(src + 4);
  bf8 v;
  v[0] = f2b(a.x); v[1] = f2b(a.y); v[2] = f2b(a.z); v[3] = f2b(a.w);
  v[4] = f2b(b.x); v[5] = f2b(b.y); v[6] = f2b(b.z); v[7] = f2b(b.w);
  *(bf8*)dst = v;
}

// C = A @ W^T, pure-bf16. 128x128 tiles, BK=64, 4 waves each 64x64.
// MODE 0: W = Wb[blockIdx.z], z<2 -> RoPE Q/K epilogue; z==2 -> V^T epilogue
// MODE 1: W = Wb[3] (Wo), f32 epilogue -> [m][n]
template <int MODE>
__launch_bounds__(256, 2)
__global__ void gemm_kernel(const short* __restrict__ Ab, const short* __restrict__ Wb,
                            short* __restrict__ Qo, short* __restrict__ Ko,
                            short* __restrict__ VTo, float* __restrict__ Fo,
                            const float2* __restrict__ rope) {
  constexpr int K = 1024;
  const int bm = blockIdx.x, bn = blockIdx.y;
  const int z = (MODE == 0) ? blockIdx.z : 3;
  const short* __restrict__ Bb = Wb + ((size_t)z << 20);

  __shared__ short As[128 * 64];
  __shared__ short Bs[128 * 64];

  const int tid = threadIdx.x;
  const int lane = tid & 63;
  const int wave = tid >> 6;
  const int wr = wave >> 1, wc = wave & 1;
  const int lg = lane >> 4, lr = lane & 15;

  f4 acc[4][4];
#pragma unroll
  for (int i = 0; i < 4; i++)
#pragma unroll
    for (int j = 0; j < 4; j++) {
      acc[i][j][0] = 0.f; acc[i][j][1] = 0.f;
      acc[i][j][2] = 0.f; acc[i][j][3] = 0.f;
    }

  const int kc = tid & 7;
  const int srow = tid >> 3;
  const int kcs = (kc ^ (srow & 7)) * 8;
  char* const Asw = (char*)As + wave * 1024;
  char* const Bsw = (char*)Bs + wave * 1024;

  for (int k0 = 0; k0 < K; k0 += 64) {
#pragma unroll
    for (int i = 0; i < 4; i++) {
      const int row = srow + i * 32;
      gload16(Ab + (size_t)(bm * 128 + row) * K + k0 + kcs, Asw + i * 4096);
      gload16(Bb + (size_t)(bn * 128 + row) * K + k0 + kcs, Bsw + i * 4096);
    }
    __syncthreads();
#pragma unroll
    for (int kk = 0; kk < 2; kk++) {
      bf8 af[4], bb[4];
#pragma unroll
      for (int mi = 0; mi < 4; mi++) {
        const int row = wr * 64 + mi * 16 + lr;
        const int lb = (row * 128 + kk * 64 + lg * 16) ^ ((row & 7) << 4);
        af[mi] = *(const bf8*)((const char*)As + lb);
      }
#pragma unroll
      for (int ni = 0; ni < 4; ni++) {
        const int row = wc * 64 + ni * 16 + lr;
        const int lb = (row * 128 + kk * 64 + lg * 16) ^ ((row & 7) << 4);
        bb[ni] = *(const bf8*)((const char*)Bs + lb);
      }
#pragma unroll
      for (int mi = 0; mi < 4; mi++)
#pragma unroll
        for (int ni = 0; ni < 4; ni++)
          acc[mi][ni] = MFMA16(af[mi], bb[ni], acc[mi][ni]);
    }
    __syncthreads();
  }

  if (MODE == 1) {
#pragma unroll
    for (int mi = 0; mi < 4; mi++) {
      const int m0 = bm * 128 + wr * 64 + mi * 16 + lg * 4;
#pragma unroll
      for (int ni = 0; ni < 4; ni++) {
        const int n = bn * 128 + wc * 64 + ni * 16 + lr;
#pragma unroll
        for (int r = 0; r < 4; r++)
          Fo[(size_t)(m0 + r) * 1024 + n] = acc[mi][ni][r];
      }
    }
    return;
  }

  if (z == 2) {  // V^T: [b][h][64][s]
#pragma unroll
    for (int mi = 0; mi < 4; mi++) {
      const int m0 = bm * 128 + wr * 64 + mi * 16 + lg * 4;
      const int b = m0 >> 11, s0 = m0 & 2047;
#pragma unroll
      for (int ni = 0; ni < 4; ni++) {
        const int n = bn * 128 + wc * 64 + ni * 16 + lr;
        ushort4 pk;
        pk.x = (unsigned short)f2b(acc[mi][ni][0]);
        pk.y = (unsigned short)f2b(acc[mi][ni][1]);
        pk.z = (unsigned short)f2b(acc[mi][ni][2]);
        pk.w = (unsigned short)f2b(acc[mi][ni][3]);
        *(ushort4*)(VTo + ((size_t)((b * 16 + (n >> 6)) * 64 + (n & 63))) * 2048 + s0) = pk;
      }
    }
  } else {  // Q or K with RoPE: [b][h][s][64]
    short* __restrict__ Out = (z == 0) ? Qo : Ko;
    const float qscale = (z == 0) ? 0.18033688011112042f : 1.0f;  // 0.125*log2(e)
#pragma unroll
    for (int mi = 0; mi < 4; mi++) {
      const int m0 = bm * 128 + wr * 64 + mi * 16 + lg * 4;
      const int b = m0 >> 11, s0 = m0 & 2047;
#pragma unroll
      for (int ni = 0; ni < 4; ni++) {
        const int n = bn * 128 + wc * 64 + ni * 16 + lr;
        const int h = n >> 6, d = n & 63;
        const float sgn = (d & 1) ? 1.0f : -1.0f;
#pragma unroll
        for (int r = 0; r < 4; r++) {
          const float v = acc[mi][ni][r];
          const float p = __shfl_xor(v, 1);
          const float2 cs = rope[((s0 + r) << 5) + (d >> 1)];
          const float res = (v * cs.x + sgn * p * cs.y) * qscale;
          Out[((size_t)(b * 16 + h) * 2048 + (s0 + r)) * 64 + d] = f2b(res);
        }
      }
    }
  }
}

// Flash attention, causal, 32x32x16 MFMA geometry.
// 2-wave (128-thr) block owns 64 q-rows; wave w owns rows [qt*64+w*32, +32).
// Both waves have IDENTICAL trip count nkv = qt+1 (zero divergence).
// Per round the block stages K(8KB)+V^T(8KB) double-buffered (global_load_lds,
// rule-21 inv-swz source). Swapped QK^T (st = MFMA32(K,Q)): lane holds a 32-kv
// slice of ONE q-row (q = lane&31, kv = (reg&3)+8*(reg>>2)+4*(lane>>5) +32n).
// Softmax: in-lane tree + 1 shfl_xor(32). P->PV A-fragment built IN REGISTERS:
// 16 pk2 + 8 v_permlane32_swap (T12) -- no P LDS, no lgkm drains.
// Defer-max; Q pre-scaled by 0.125*log2e (exp2 domain).
__launch_bounds__(128, 2)
__global__ void attn_kernel(const short* __restrict__ Qg, const short* __restrict__ Kg,
                            const short* __restrict__ Vg, short* __restrict__ AO) {
  const int S = 2048;
  const int id = blockIdx.x;
  const int xcd = id & 7;
  const int rest = id >> 3;             // 0..127
  const int bh = xcd * 4 + (rest & 3);  // XCD-clustered: 4 bh per XCD
  const int qt = 31 - (rest >> 2);      // longest-first
  const int tid = threadIdx.x;
  const int lane = tid & 63, wave = tid >> 6;
  const int l31 = lane & 31, hi = lane >> 5;
  const short* __restrict__ Qp = Qg + (size_t)bh * S * 64;
  const short* __restrict__ Kp = Kg + (size_t)bh * S * 64;
  const short* __restrict__ Vp = Vg + (size_t)bh * 64 * S;

  __shared__ short KB[2][64 * 64];  // K tile [kv][d], swizzled (8KB each)
  __shared__ short VB[2][64 * 64];  // V^T tile [d][kv], swizzled

  const int qbase = qt * 64 + wave * 32;
  const int nkv = qt + 1;  // same for both waves

  // staging: wave w covers rows w*32 + c*8 + (lane>>3), c = 0..3, chunk lane&7
  const int srow = lane >> 3;                // 0..7
  const int chsw = ((lane & 7) ^ srow) * 8;  // inverse-swizzled chunk (shorts)

#define STAGE(buf, kvb_)                                                          \
  do {                                                                            \
    _Pragma("unroll") for (int c = 0; c < 4; c++) {                               \
      const int rr = wave * 32 + c * 8 + srow;                                    \
      gload16(Kp + (size_t)((kvb_) + rr) * 64 + chsw,                             \
              (char*)KB[buf] + (wave * 32 + c * 8) * 128);                        \
      gload16(Vp + (size_t)rr * 2048 + (kvb_) + chsw,                             \
              (char*)VB[buf] + (wave * 32 + c * 8) * 128);                        \
    }                                                                             \
  } while (0)

  // Q B-fragments: lane holds Q[d = ks*16 + hi*8 + e][q = qbase + l31]
  bf8 qf[4];
#pragma unroll
  for (int ks = 0; ks < 4; ks++)
    qf[ks] = *(const bf8*)(Qp + (size_t)(qbase + l31) * 64 + ks * 16 + hi * 8);

  f16f o0, o1;
#pragma unroll
  for (int i = 0; i < 16; i++) { o0[i] = 0.f; o1[i] = 0.f; }
  float mrun = -1e30f, lsum = 0.f;

  const int rsw = (l31 & 7) << 4;  // row&7 is l31&7 for all fragment rows

  STAGE(0, 0);
  __syncthreads();

  for (int kb = 0; kb < nkv; kb++) {
    const int kvb = kb * 64;
    const int cur = kb & 1;

    if (kb + 1 < nkv) STAGE(cur ^ 1, kvb + 64);

    const char* Kc = (const char*)KB[cur];
    const char* Vc = (const char*)VB[cur];

    // swapped QK^T: st_n[reg] = S^T[kv = kvb + 32n + (reg&3)+8*(reg>>2)+4hi][q]
    f16f st0, st1;
#pragma unroll
    for (int i = 0; i < 16; i++) { st0[i] = 0.f; st1[i] = 0.f; }
    __builtin_amdgcn_s_setprio(1);
#pragma unroll
    for (int ks = 0; ks < 4; ks++) {
      const int off = ks * 32 + hi * 16;
      const bf8 k0 = *(const bf8*)(Kc + l31 * 128 + (off ^ rsw));
      const bf8 k1 = *(const bf8*)(Kc + (32 + l31) * 128 + (off ^ rsw));
      st0 = MFMA32(k0, qf[ks], st0);
      st1 = MFMA32(k1, qf[ks], st1);
    }
    __builtin_amdgcn_s_setprio(0);

    if (kvb + 63 > qbase) {  // causal mask (diagonal round)
      const int q = qbase + l31;
#pragma unroll
      for (int reg = 0; reg < 16; reg++) {
        const int kv = kvb + (reg & 3) + 8 * (reg >> 2) + 4 * hi;
        if (kv > q) st0[reg] = -1e9f;
        if (kv + 32 > q) st1[reg] = -1e9f;
      }
    }

    // row max: in-lane tree over 32 + one cross-half shfl
    float m0 = fmaxf(st0[0], st1[0]);
#pragma unroll
    for (int reg = 1; reg < 16; reg++) m0 = fmaxf(m0, fmaxf(st0[reg], st1[reg]));
    m0 = fmaxf(m0, __shfl_xor(m0, 32));

    // defer-max: rescale only on threshold growth (exp2 domain)
    if (__any(m0 - mrun > 8.0f)) {
      const float mn = fmaxf(mrun, m0);
      const float corr = __builtin_amdgcn_exp2f(mrun - mn);
      mrun = mn;
      lsum *= corr;
#pragma unroll
      for (int reg = 0; reg < 16; reg++) {
        const int qo = (reg & 3) + 8 * (reg >> 2) + 4 * hi;
        const float co = __shfl(corr, qo);  // corr lives on lane qo (q = l31)
        o0[reg] *= co;
        o1[reg] *= co;
      }
    }

    // P = exp2(st - m), in place; per-lane partial sum
#pragma unroll
    for (int reg = 0; reg < 16; reg++) {
      st0[reg] = __builtin_amdgcn_exp2f(st0[reg] - mrun);
      st1[reg] = __builtin_amdgcn_exp2f(st1[reg] - mrun);
      lsum += st0[reg] + st1[reg];
    }

    // build PV A-fragments in registers: pa[k2] covers kv [16k2, 16k2+16)
    // words = {x0', x1', y0', y1'} where (x0',y0') = permlane32_swap(x0,y0)
    bf8 pa[4];
#pragma unroll
    for (int k2 = 0; k2 < 4; k2++) {
      const f16f& pn = (k2 < 2) ? st0 : st1;
      const int bs = (k2 & 1) * 8;
      uint32_t x0 = pk2(pn[bs + 0], pn[bs + 1]);
      uint32_t y0 = pk2(pn[bs + 4], pn[bs + 5]);
      uint32_t x1 = pk2(pn[bs + 2], pn[bs + 3]);
      uint32_t y1 = pk2(pn[bs + 6], pn[bs + 7]);
      asm volatile("v_permlane32_swap_b32 %0, %1" : "+v"(x0), "+v"(y0));
      asm volatile("v_permlane32_swap_b32 %0, %1" : "+v"(x1), "+v"(y1));
      pa[k2] = mk_bf8(x0, x1, y0, y1);
    }

    // PV: o_dt += P[q][kv16] * V[kv16][d]; V B-frag from V^T rows
    __builtin_amdgcn_s_setprio(1);
#pragma unroll
    for (int k2 = 0; k2 < 4; k2++) {
      const int off = k2 * 32 + hi * 16;
      const bf8 v0 = *(const bf8*)(Vc + l31 * 128 + (off ^ rsw));
      const bf8 v1 = *(const bf8*)(Vc + (32 + l31) * 128 + (off ^ rsw));
      o0 = MFMA32(pa[k2], v0, o0);
      o1 = MFMA32(pa[k2], v1, o1);
    }
    __builtin_amdgcn_s_setprio(0);

    __syncthreads();  // drains vmcnt: next staged buffer complete
  }

  // finalize: cross-half sum, redistribute 1/lsum to o-layout, write AO
  const float s = lsum + __shfl_xor(lsum, 32);
  const float inv = 1.0f / s;
  const int b = bh >> 4, h = bh & 15;
#pragma unroll
  for (int reg = 0; reg < 16; reg++) {
    const int qo = (reg & 3) + 8 * (reg >> 2) + 4 * hi;
    const float io = __shfl(inv, qo);
    const int q = qbase + qo;
    const size_t base = ((size_t)b * 2048 + q) * 1024 + h * 64 + l31;
    AO[base] = f2b(o0[reg] * io);
    AO[base + 32] = f2b(o1[reg] * io);
  }
#undef STAGE
}

extern "C" void kernel_launch(void* const* d_in, const int* in_sizes, int n_in,
                              void* d_out, int out_size, void* d_ws, size_t ws_size,
                              hipStream_t stream) {
  const float* x  = (const float*)d_in[0];
  const float* wq = (const float*)d_in[1];
  const float* wk = (const float*)d_in[2];
  const float* wv = (const float*)d_in[3];
  const float* wo = (const float*)d_in[4];
  float* out = (float*)d_out;

  char* ws = (char*)d_ws;
  short*  Qb  = (short*)(ws);                       // 8 MB  [b][h][s][64] bf16 (pre-scaled)
  short*  Kb  = (short*)(ws + (8ull  << 20));       // 8 MB
  short*  VTb = (short*)(ws + (16ull << 20));       // 8 MB  [b][h][64][s] bf16
  short*  AOb = (short*)(ws + (24ull << 20));       // 8 MB  [b][s][1024] bf16 (aliases xb)
  short*  xb  = AOb;                                // xb dead before attn writes AOb
  short*  Wb  = (short*)(ws + (32ull << 20));       // 8 MB  [4][1024][1024] bf16
  float2* tab = (float2*)(ws + (40ull << 20));      // 512 KB rope table

  convert_kernel<<<4352, 256, 0, stream>>>(x, wq, wk, wv, wo, xb, Wb, tab);
  gemm_kernel<0><<<dim3(32, 8, 3), 256, 0, stream>>>(
      xb, Wb, Qb, Kb, VTb, nullptr, tab);
  attn_kernel<<<1024, 128, 0, stream>>>(Qb, Kb, VTb, AOb);
  gemm_kernel<1><<<dim3(32, 8, 1), 256, 0, stream>>>(
      AOb, Wb, nullptr, nullptr, nullptr, out, nullptr);
}